// Round 2
// baseline (706.916 us; speedup 1.0000x reference)
//
#include <hip/hip_runtime.h>

// Problem constants (from reference): B=128, N=512, H=256, F_JET=8, gin=776.
#define B_   128
#define N_   512
#define H_   256
#define FJ   8
#define ROWS (B_ * N_)          // 65536 flattened vertex rows
#define NEGV (-1e9f)

typedef __attribute__((ext_vector_type(8))) __bf16 b16x8;   // one MFMA A/B fragment (4 VGPRs)
typedef __attribute__((ext_vector_type(4))) float  f32x4;   // one MFMA C/D fragment

static __device__ inline f32x4 MFMA(b16x8 a, b16x8 b, f32x4 c) {
  return __builtin_amdgcn_mfma_f32_16x16x32_bf16(a, b, c, 0, 0, 0);
}

// global -> LDS direct copy, 16B per lane. lptr must be wave-uniform; HW adds lane*16.
static __device__ inline void gld16(const void* g, void* l) {
  __builtin_amdgcn_global_load_lds(
      (const __attribute__((address_space(1))) void*)g,
      (__attribute__((address_space(3))) void*)(uintptr_t)l,
      16, 0, 0);
}

// ---------------------------------------------------------------------------
// Prep: transpose/convert weights once per launch (same as R1).
// ---------------------------------------------------------------------------
__global__ void k_prep(const float* __restrict__ Wa, const float* __restrict__ Wm,
                       const float* __restrict__ Wz, const float* __restrict__ Wr,
                       const float* __restrict__ Wh,
                       __bf16* __restrict__ WaT_hi, __bf16* __restrict__ WaT_lo,
                       __bf16* __restrict__ WmT,    __bf16* __restrict__ WzrT,
                       __bf16* __restrict__ WhcT) {
  int idx = blockIdx.x * 256 + threadIdx.x;
  if (idx < 65536) {
    int d = idx >> 8, k = idx & 255;
    float w = Wa[k * 256 + d];
    __bf16 hb = (__bf16)w;
    WaT_hi[d * 256 + k] = hb;
    WaT_lo[d * 256 + k] = (__bf16)(w - (float)hb);
  } else if (idx < 131072) {
    int t = idx - 65536;
    int d = t >> 8, k = t & 255;
    WmT[d * 256 + k] = (__bf16)Wm[k * 256 + d];
  } else if (idx < 131072 + 262144) {
    int t = idx - 131072;
    int n = t >> 9, k = t & 511;
    const float* src = (n < 256) ? Wz : Wr;
    int np  = n & 255;
    int row = (k < 256) ? k : (264 + k);   // 520 + (k - 256)
    WzrT[n * 512 + k] = (__bf16)src[row * 256 + np];
  } else {
    int t = idx - (131072 + 262144);       // < 131072
    int n = t >> 9, k = t & 511;
    int row = (k < 256) ? k : (264 + k);
    WhcT[n * 512 + k] = (__bf16)Wh[row * 256 + n];
  }
}

// h_mean[b][d] = mean_n h[b][n][d]
__global__ void k_hmean(const float* __restrict__ h, float* __restrict__ hmean) {
  int b = blockIdx.x, d = threadIdx.x;
  const float* p = h + (size_t)b * N_ * H_ + d;
  float s = 0.f;
  #pragma unroll 8
  for (int n = 0; n < N_; ++n) s += p[n * H_];
  hmean[b * H_ + d] = s * (1.f / N_);
}

// Per-batch GRU constants: c_*[b][d] = bias[d] + h_mean[b]·W*[256:512,d] + jets[b]·W*[512:520,d]
__global__ void k_cvec(const float* __restrict__ hmean, const float* __restrict__ jets,
                       const float* __restrict__ Wz, const float* __restrict__ Wr,
                       const float* __restrict__ Wh,
                       const float* __restrict__ bz, const float* __restrict__ br,
                       const float* __restrict__ bh,
                       float* __restrict__ cz, float* __restrict__ cr, float* __restrict__ ch) {
  __shared__ float hm[H_];
  __shared__ float jt[FJ];
  int b = blockIdx.x, d = threadIdx.x;
  hm[d] = hmean[b * H_ + d];
  if (d < FJ) jt[d] = jets[b * FJ + d];
  __syncthreads();
  float az = bz[d], ar = br[d], ah = bh[d];
  #pragma unroll 4
  for (int k = 0; k < H_; ++k) {
    float m = hm[k];
    az += m * Wz[(256 + k) * 256 + d];
    ar += m * Wr[(256 + k) * 256 + d];
    ah += m * Wh[(256 + k) * 256 + d];
  }
  #pragma unroll
  for (int f = 0; f < FJ; ++f) {
    float j = jt[f];
    az += j * Wz[(512 + f) * 256 + d];
    ar += j * Wr[(512 + f) * 256 + d];
    ah += j * Wh[(512 + f) * 256 + d];
  }
  cz[b * H_ + d] = az;
  cr[b * H_ + d] = ar;
  ch[b * H_ + d] = ah;
}

// ---------------------------------------------------------------------------
// K split images, pre-swizzled in the exact LDS byte layout k_attn2 expects:
// row j holds 32 16B-chunks; chunk c (elems k=c*8..c*8+7) stored at slot c^(j&7).
// ---------------------------------------------------------------------------
__global__ void k_ksplit(const float* __restrict__ h, __bf16* __restrict__ Khi,
                         __bf16* __restrict__ Klo, int use_klo) {
  int t  = blockIdx.x * 256 + threadIdx.x;   // chunk id: 128*512*32 = 2,097,152
  int c  = t & 31;
  int rj = t >> 5;                            // b*512 + j
  const float* p = h + (size_t)rj * 256 + c * 8;
  f32x4 v0 = *(const f32x4*)p;
  f32x4 v1 = *(const f32x4*)(p + 4);
  b16x8 hv, lv;
  #pragma unroll
  for (int e = 0; e < 4; ++e) {
    __bf16 h0 = (__bf16)v0[e], h1 = (__bf16)v1[e];
    hv[e] = h0; hv[4 + e] = h1;
    lv[e]     = (__bf16)(v0[e] - (float)h0);
    lv[4 + e] = (__bf16)(v1[e] - (float)h1);
  }
  size_t o = (size_t)rj * 256 + (size_t)((c ^ (rj & 7)) * 8);
  *(b16x8*)&Khi[o] = hv;
  if (use_klo) *(b16x8*)&Klo[o] = lv;
}

// ---------------------------------------------------------------------------
// q = h @ Wa + ba via 3-term bf16 split. Grid (512 m-tiles, 2 n-tiles):
// same-m pair at ids {m, m+512} -> same XCD (512 % 8 == 0).
// ---------------------------------------------------------------------------
__global__ __launch_bounds__(256) void k_gemm_q(
    const float* __restrict__ h, const __bf16* __restrict__ WaT_hi,
    const __bf16* __restrict__ WaT_lo, const float* __restrict__ ba,
    float* __restrict__ q) {
  __shared__ __bf16 Ahi[128][40], Alo[128][40], Bhi[128][40], Blo[128][40];
  const int tid = threadIdx.x, lane = tid & 63, wave = tid >> 6;
  const int g = lane >> 4, m16 = lane & 15;
  const int wr = (wave >> 1) * 64, wc = (wave & 1) * 64;
  const int m0 = blockIdx.x * 128, n0 = blockIdx.y * 128;
  f32x4 acc[4][4] = {};
  for (int k0 = 0; k0 < 256; k0 += 32) {
    __syncthreads();
    #pragma unroll
    for (int i = 0; i < 2; ++i) {
      int c = tid + i * 256;                // 512 chunks of 8 elements
      int row = c >> 2, kc = (c & 3) * 8;
      const float* p = h + (size_t)(m0 + row) * 256 + k0 + kc;
      f32x4 v0 = *(const f32x4*)p;
      f32x4 v1 = *(const f32x4*)(p + 4);
      b16x8 hv, lv;
      #pragma unroll
      for (int e = 0; e < 4; ++e) {
        __bf16 h0 = (__bf16)v0[e], h1 = (__bf16)v1[e];
        hv[e] = h0; hv[4 + e] = h1;
        lv[e]     = (__bf16)(v0[e] - (float)h0);
        lv[4 + e] = (__bf16)(v1[e] - (float)h1);
      }
      *(b16x8*)&Ahi[row][kc] = hv;
      *(b16x8*)&Alo[row][kc] = lv;
      size_t boff = (size_t)(n0 + row) * 256 + k0 + kc;
      *(b16x8*)&Bhi[row][kc] = *(const b16x8*)(WaT_hi + boff);
      *(b16x8*)&Blo[row][kc] = *(const b16x8*)(WaT_lo + boff);
    }
    __syncthreads();
    b16x8 ah[4], al[4], bh4[4], bl4[4];
    #pragma unroll
    for (int mi = 0; mi < 4; ++mi) {
      ah[mi] = *(const b16x8*)&Ahi[wr + mi * 16 + m16][8 * g];
      al[mi] = *(const b16x8*)&Alo[wr + mi * 16 + m16][8 * g];
    }
    #pragma unroll
    for (int ni = 0; ni < 4; ++ni) {
      bh4[ni] = *(const b16x8*)&Bhi[wc + ni * 16 + m16][8 * g];
      bl4[ni] = *(const b16x8*)&Blo[wc + ni * 16 + m16][8 * g];
    }
    #pragma unroll
    for (int mi = 0; mi < 4; ++mi)
      #pragma unroll
      for (int ni = 0; ni < 4; ++ni) {
        acc[mi][ni] = MFMA(ah[mi], bh4[ni], acc[mi][ni]);
        acc[mi][ni] = MFMA(ah[mi], bl4[ni], acc[mi][ni]);
        acc[mi][ni] = MFMA(al[mi], bh4[ni], acc[mi][ni]);
      }
  }
  #pragma unroll
  for (int mi = 0; mi < 4; ++mi)
    #pragma unroll
    for (int ni = 0; ni < 4; ++ni) {
      int gcol = n0 + wc + ni * 16 + m16;
      float bias = ba[gcol];
      #pragma unroll
      for (int r = 0; r < 4; ++r) {
        int grow = m0 + wr + mi * 16 + 4 * g + r;
        q[(size_t)grow * 256 + gcol] = acc[mi][ni][r] + bias;
      }
    }
}

// ---------------------------------------------------------------------------
// hmT[b][d][n] = bf16( (h[b] @ Wm + bm)^T ). Grid (128 batches, 8 tiles):
// all 8 tiles of batch b at ids b+128*t -> same XCD.
// ---------------------------------------------------------------------------
__global__ __launch_bounds__(256) void k_gemm_hmT(
    const float* __restrict__ h, const __bf16* __restrict__ WmT,
    const float* __restrict__ bm, __bf16* __restrict__ hmT) {
  __shared__ __bf16 At[128][72], Bt[128][72];
  const int tid = threadIdx.x, lane = tid & 63, wave = tid >> 6;
  const int g = lane >> 4, m16 = lane & 15;
  const int wr = (wave >> 1) * 64, wc = (wave & 1) * 64;
  const int b = blockIdx.x;
  const int m0 = (blockIdx.y >> 2) * 128, n0 = (blockIdx.y & 3) * 128;
  const float* hb = h + (size_t)b * N_ * H_;
  f32x4 acc[4][4] = {};
  for (int k0 = 0; k0 < 256; k0 += 64) {
    __syncthreads();
    #pragma unroll
    for (int i = 0; i < 4; ++i) {
      int c = tid + i * 256;                // 1024 chunks of 8
      int row = c >> 3, kc = (c & 7) * 8;
      *(b16x8*)&At[row][kc] = *(const b16x8*)(WmT + (size_t)(m0 + row) * 256 + k0 + kc);
      const float* p = hb + (size_t)(n0 + row) * 256 + k0 + kc;
      f32x4 v0 = *(const f32x4*)p, v1 = *(const f32x4*)(p + 4);
      b16x8 hv;
      #pragma unroll
      for (int e = 0; e < 4; ++e) { hv[e] = (__bf16)v0[e]; hv[4 + e] = (__bf16)v1[e]; }
      *(b16x8*)&Bt[row][kc] = hv;
    }
    __syncthreads();
    #pragma unroll
    for (int ks = 0; ks < 2; ++ks) {
      b16x8 af[4], bf4[4];
      #pragma unroll
      for (int mi = 0; mi < 4; ++mi) af[mi]  = *(const b16x8*)&At[wr + mi * 16 + m16][ks * 32 + 8 * g];
      #pragma unroll
      for (int ni = 0; ni < 4; ++ni) bf4[ni] = *(const b16x8*)&Bt[wc + ni * 16 + m16][ks * 32 + 8 * g];
      #pragma unroll
      for (int mi = 0; mi < 4; ++mi)
        #pragma unroll
        for (int ni = 0; ni < 4; ++ni)
          acc[mi][ni] = MFMA(af[mi], bf4[ni], acc[mi][ni]);
    }
  }
  #pragma unroll
  for (int mi = 0; mi < 4; ++mi)
    #pragma unroll
    for (int r = 0; r < 4; ++r) {
      int d = m0 + wr + mi * 16 + 4 * g + r;
      float bias = bm[d];
      #pragma unroll
      for (int ni = 0; ni < 4; ++ni) {
        int n = n0 + wc + ni * 16 + m16;
        hmT[(size_t)b * H_ * N_ + (size_t)d * N_ + n] = (__bf16)(acc[mi][ni][r] + bias);
      }
    }
}

// ---------------------------------------------------------------------------
// Flash attention + DTNN message, v2: prestaged pre-swizzled K images,
// global_load_lds double-buffered pipeline, grid (batch, i-tile) for XCD
// locality. KLO selects 3-term (q-split + K-split) vs 2-term (q-split only).
// ---------------------------------------------------------------------------
template<bool KLO>
__global__ __launch_bounds__(256) void k_attn2(
    const float* __restrict__ q, const float* __restrict__ mask,
    const __bf16* __restrict__ hmT, const __bf16* __restrict__ Khi_img,
    const __bf16* __restrict__ Klo_img, __bf16* __restrict__ msg) {
  constexpr int TILE = 16384;                 // 32 rows * 512B
  constexpr int BUFB = KLO ? 2 * TILE : TILE; // bytes per double-buffer half
  __shared__ __align__(16) uint8_t KB[2 * BUFB];
  __shared__ __bf16 Plds[4][16][40];
  const int tid = threadIdx.x, lane = tid & 63, wave = tid >> 6;
  const int g = lane >> 4, m16 = lane & 15;
  const int b = blockIdx.x, i0 = blockIdx.y * 64;

  const uint8_t* hi_src = (const uint8_t*)(Khi_img + (size_t)b * N_ * H_);
  const uint8_t* lo_src = (const uint8_t*)(Klo_img + (size_t)b * N_ * H_);

  // Q fragments in registers (rows i0 + wave*16 + m16), split hi/lo
  const float* qp = q + (size_t)(b * N_ + i0 + wave * 16 + m16) * H_ + 8 * g;
  b16x8 qhi[8], qlo[8];
  #pragma unroll
  for (int kb = 0; kb < 8; ++kb) {
    f32x4 v0 = *(const f32x4*)(qp + kb * 32);
    f32x4 v1 = *(const f32x4*)(qp + kb * 32 + 4);
    #pragma unroll
    for (int e = 0; e < 4; ++e) {
      __bf16 h0 = (__bf16)v0[e], h1 = (__bf16)v1[e];
      qhi[kb][e] = h0; qhi[kb][4 + e] = h1;
      qlo[kb][e]     = (__bf16)(v0[e] - (float)h0);
      qlo[kb][4 + e] = (__bf16)(v1[e] - (float)h1);
    }
  }

  f32x4 o[16] = {};
  float mrun[4], lrun[4];
  #pragma unroll
  for (int r = 0; r < 4; ++r) { mrun[r] = -3.0e38f; lrun[r] = 0.f; }

  const __bf16* hvb = hmT + (size_t)b * H_ * N_;

  auto stage = [&](int jt, int buf) {
    const uint8_t* hs = hi_src + jt * TILE + tid * 16;
    uint8_t* lb = &KB[buf * BUFB] + wave * 1024;   // wave-uniform LDS base
    #pragma unroll
    for (int i = 0; i < 4; ++i) gld16(hs + i * 4096, lb + i * 4096);
    if constexpr (KLO) {
      const uint8_t* ls = lo_src + jt * TILE + tid * 16;
      uint8_t* lb2 = &KB[buf * BUFB + TILE] + wave * 1024;
      #pragma unroll
      for (int i = 0; i < 4; ++i) gld16(ls + i * 4096, lb2 + i * 4096);
    }
  };

  stage(0, 0);
  asm volatile("s_waitcnt vmcnt(0)" ::: "memory");
  __syncthreads();

  for (int jt = 0; jt < 16; ++jt) {
    const int cur = jt & 1, j0 = jt * 32;
    if (jt < 15) stage(jt + 1, cur ^ 1);
    const uint8_t* khb = &KB[cur * BUFB];
    const uint8_t* klb = &KB[cur * BUFB + TILE];

    // S = q · K^T, 16 rows x 32 cols per wave; XOR-deswizzled chunk reads
    f32x4 s[2] = {};
    #pragma unroll
    for (int kb = 0; kb < 8; ++kb)
      #pragma unroll
      for (int cf = 0; cf < 2; ++cf) {
        const int jr = cf * 16 + m16;
        const uint32_t off = (uint32_t)jr * 512 + (uint32_t)(((kb * 4 + g) ^ (m16 & 7)) << 4);
        b16x8 kh = *(const b16x8*)(khb + off);
        s[cf] = MFMA(qhi[kb], kh, s[cf]);
        if constexpr (KLO) {
          b16x8 kl = *(const b16x8*)(klb + off);
          s[cf] = MFMA(qhi[kb], kl, s[cf]);
        }
        s[cf] = MFMA(qlo[kb], kh, s[cf]);
      }
    // column mask
    #pragma unroll
    for (int cf = 0; cf < 2; ++cf) {
      float cm  = mask[b * N_ + j0 + cf * 16 + m16];
      float add = NEGV * (1.f - cm);
      #pragma unroll
      for (int r = 0; r < 4; ++r) s[cf][r] += add;
    }
    // online softmax (rows live in 16-lane groups)
    float p_[2][4];
    #pragma unroll
    for (int r = 0; r < 4; ++r) {
      float mx = fmaxf(s[0][r], s[1][r]);
      #pragma unroll
      for (int off = 1; off < 16; off <<= 1) mx = fmaxf(mx, __shfl_xor(mx, off, 64));
      float mnew  = fmaxf(mrun[r], mx);
      float alpha = __expf(mrun[r] - mnew);
      float ps = 0.f;
      #pragma unroll
      for (int cf = 0; cf < 2; ++cf) {
        float pv = __expf(s[cf][r] - mnew);
        p_[cf][r] = pv; ps += pv;
      }
      #pragma unroll
      for (int off = 1; off < 16; off <<= 1) ps += __shfl_xor(ps, off, 64);
      lrun[r] = lrun[r] * alpha + ps;
      mrun[r] = mnew;
      #pragma unroll
      for (int c2 = 0; c2 < 16; ++c2) o[c2][r] *= alpha;
    }
    // P -> LDS (C-layout) -> A-fragment layout (wave-local round trip)
    #pragma unroll
    for (int cf = 0; cf < 2; ++cf)
      #pragma unroll
      for (int r = 0; r < 4; ++r)
        Plds[wave][4 * g + r][cf * 16 + m16] = (__bf16)p_[cf][r];
    asm volatile("s_waitcnt lgkmcnt(0)" ::: "memory");
    __builtin_amdgcn_sched_barrier(0);
    b16x8 pa = *(const b16x8*)&Plds[wave][m16][8 * g];
    // PV: o += P @ hm_tile  (B-frags straight from hmT, L2-hot)
    #pragma unroll
    for (int c2 = 0; c2 < 16; ++c2) {
      const __bf16* vp = hvb + (size_t)(c2 * 16 + m16) * N_ + j0 + 8 * g;
      b16x8 vv = *(const b16x8*)vp;
      o[c2] = MFMA(pa, vv, o[c2]);
    }
    asm volatile("s_waitcnt vmcnt(0)" ::: "memory");
    __syncthreads();
  }

  // epilogue: msg = tanh(row_mask * O / l)
  #pragma unroll
  for (int r = 0; r < 4; ++r) {
    int irow = i0 + wave * 16 + 4 * g + r;
    float rm  = mask[b * N_ + irow];
    float inv = rm / lrun[r];
    #pragma unroll
    for (int c2 = 0; c2 < 16; ++c2) {
      float val = tanhf(o[c2][r] * inv);
      msg[(size_t)(b * N_ + irow) * H_ + c2 * 16 + m16] = (__bf16)val;
    }
  }
}

// ---------------------------------------------------------------------------
// Fallback attention (R1 structure, in-kernel staging) in case ws is tight.
// Grid swapped to (batch, i-tile) for XCD locality.
// ---------------------------------------------------------------------------
__global__ __launch_bounds__(256) void k_attn_fb(
    const float* __restrict__ q, const float* __restrict__ h,
    const float* __restrict__ mask, const __bf16* __restrict__ hmT,
    __bf16* __restrict__ msg) {
  __shared__ __bf16 Khi[32][264], Klo[32][264];
  __shared__ __bf16 Plds[4][16][40];
  const int tid = threadIdx.x, lane = tid & 63, wave = tid >> 6;
  const int g = lane >> 4, m16 = lane & 15;
  const int b = blockIdx.x, i0 = blockIdx.y * 64;

  const float* qp = q + (size_t)(b * N_ + i0 + wave * 16 + m16) * H_ + 8 * g;
  b16x8 qhi[8], qlo[8];
  #pragma unroll
  for (int kb = 0; kb < 8; ++kb) {
    f32x4 v0 = *(const f32x4*)(qp + kb * 32);
    f32x4 v1 = *(const f32x4*)(qp + kb * 32 + 4);
    #pragma unroll
    for (int e = 0; e < 4; ++e) {
      __bf16 h0 = (__bf16)v0[e], h1 = (__bf16)v1[e];
      qhi[kb][e] = h0; qhi[kb][4 + e] = h1;
      qlo[kb][e]     = (__bf16)(v0[e] - (float)h0);
      qlo[kb][4 + e] = (__bf16)(v1[e] - (float)h1);
    }
  }

  f32x4 o[16] = {};
  float mrun[4], lrun[4];
  #pragma unroll
  for (int r = 0; r < 4; ++r) { mrun[r] = -3.0e38f; lrun[r] = 0.f; }

  const __bf16* hvb = hmT + (size_t)b * H_ * N_;
  const float*  hb  = h   + (size_t)b * N_ * H_;

  for (int jt = 0; jt < 16; ++jt) {
    int j0 = jt * 32;
    __syncthreads();
    {
      int row = tid >> 3, ks0 = (tid & 7) * 32;
      const float* p = hb + (size_t)(j0 + row) * H_ + ks0;
      #pragma unroll
      for (int c2 = 0; c2 < 4; ++c2) {
        f32x4 v0 = *(const f32x4*)(p + c2 * 8);
        f32x4 v1 = *(const f32x4*)(p + c2 * 8 + 4);
        b16x8 hv, lv;
        #pragma unroll
        for (int e = 0; e < 4; ++e) {
          __bf16 h0 = (__bf16)v0[e], h1 = (__bf16)v1[e];
          hv[e] = h0; hv[4 + e] = h1;
          lv[e]     = (__bf16)(v0[e] - (float)h0);
          lv[4 + e] = (__bf16)(v1[e] - (float)h1);
        }
        *(b16x8*)&Khi[row][ks0 + c2 * 8] = hv;
        *(b16x8*)&Klo[row][ks0 + c2 * 8] = lv;
      }
    }
    __syncthreads();

    f32x4 s[2] = {};
    #pragma unroll
    for (int kb = 0; kb < 8; ++kb)
      #pragma unroll
      for (int cf = 0; cf < 2; ++cf) {
        b16x8 kh = *(const b16x8*)&Khi[cf * 16 + m16][kb * 32 + 8 * g];
        b16x8 kl = *(const b16x8*)&Klo[cf * 16 + m16][kb * 32 + 8 * g];
        s[cf] = MFMA(qhi[kb], kh, s[cf]);
        s[cf] = MFMA(qhi[kb], kl, s[cf]);
        s[cf] = MFMA(qlo[kb], kh, s[cf]);
      }
    #pragma unroll
    for (int cf = 0; cf < 2; ++cf) {
      float cm  = mask[b * N_ + j0 + cf * 16 + m16];
      float add = NEGV * (1.f - cm);
      #pragma unroll
      for (int r = 0; r < 4; ++r) s[cf][r] += add;
    }
    float p_[2][4];
    #pragma unroll
    for (int r = 0; r < 4; ++r) {
      float mx = fmaxf(s[0][r], s[1][r]);
      #pragma unroll
      for (int off = 1; off < 16; off <<= 1) mx = fmaxf(mx, __shfl_xor(mx, off, 64));
      float mnew  = fmaxf(mrun[r], mx);
      float alpha = __expf(mrun[r] - mnew);
      float ps = 0.f;
      #pragma unroll
      for (int cf = 0; cf < 2; ++cf) {
        float pv = __expf(s[cf][r] - mnew);
        p_[cf][r] = pv; ps += pv;
      }
      #pragma unroll
      for (int off = 1; off < 16; off <<= 1) ps += __shfl_xor(ps, off, 64);
      lrun[r] = lrun[r] * alpha + ps;
      mrun[r] = mnew;
      #pragma unroll
      for (int c2 = 0; c2 < 16; ++c2) o[c2][r] *= alpha;
    }
    #pragma unroll
    for (int cf = 0; cf < 2; ++cf)
      #pragma unroll
      for (int r = 0; r < 4; ++r)
        Plds[wave][4 * g + r][cf * 16 + m16] = (__bf16)p_[cf][r];
    asm volatile("s_waitcnt lgkmcnt(0)" ::: "memory");
    __builtin_amdgcn_sched_barrier(0);
    b16x8 pa = *(const b16x8*)&Plds[wave][m16][8 * g];
    #pragma unroll
    for (int c2 = 0; c2 < 16; ++c2) {
      const __bf16* vp = hvb + (size_t)(c2 * 16 + m16) * N_ + j0 + 8 * g;
      b16x8 vv = *(const b16x8*)vp;
      o[c2] = MFMA(pa, vv, o[c2]);
    }
  }

  #pragma unroll
  for (int r = 0; r < 4; ++r) {
    int irow = i0 + wave * 16 + 4 * g + r;
    float rm  = mask[b * N_ + irow];
    float inv = rm / lrun[r];
    #pragma unroll
    for (int c2 = 0; c2 < 16; ++c2) {
      float val = tanhf(o[c2][r] * inv);
      msg[(size_t)(b * N_ + irow) * H_ + c2 * 16 + m16] = (__bf16)val;
    }
  }
}

// ---------------------------------------------------------------------------
// Gates: [z|r]_pre = [msg|h] @ WzrT^T + c_{z|r};  z = sigmoid, rh = sigmoid(r)*h
// Grid (512 m-tiles, 4 n-tiles): same-m blocks same XCD.
// ---------------------------------------------------------------------------
__global__ __launch_bounds__(256) void k_gemm_zr(
    const __bf16* __restrict__ msg, const float* __restrict__ h,
    const __bf16* __restrict__ WzrT, const float* __restrict__ cz,
    const float* __restrict__ cr, __bf16* __restrict__ z, __bf16* __restrict__ rh) {
  __shared__ __bf16 At[128][72], Bt[128][72];
  const int tid = threadIdx.x, lane = tid & 63, wave = tid >> 6;
  const int g = lane >> 4, m16 = lane & 15;
  const int wr = (wave >> 1) * 64, wc = (wave & 1) * 64;
  const int m0 = blockIdx.x * 128, n0 = blockIdx.y * 128;
  f32x4 acc[4][4] = {};
  for (int k0 = 0; k0 < 512; k0 += 64) {
    __syncthreads();
    #pragma unroll
    for (int i = 0; i < 4; ++i) {
      int c = tid + i * 256;
      int row = c >> 3, kc = (c & 7) * 8;
      if (k0 < 256) {
        *(b16x8*)&At[row][kc] = *(const b16x8*)(msg + (size_t)(m0 + row) * 256 + k0 + kc);
      } else {
        const float* p = h + (size_t)(m0 + row) * 256 + (k0 - 256) + kc;
        f32x4 v0 = *(const f32x4*)p, v1 = *(const f32x4*)(p + 4);
        b16x8 hv;
        #pragma unroll
        for (int e = 0; e < 4; ++e) { hv[e] = (__bf16)v0[e]; hv[4 + e] = (__bf16)v1[e]; }
        *(b16x8*)&At[row][kc] = hv;
      }
      *(b16x8*)&Bt[row][kc] = *(const b16x8*)(WzrT + (size_t)(n0 + row) * 512 + k0 + kc);
    }
    __syncthreads();
    #pragma unroll
    for (int ks = 0; ks < 2; ++ks) {
      b16x8 af[4], bf4[4];
      #pragma unroll
      for (int mi = 0; mi < 4; ++mi) af[mi]  = *(const b16x8*)&At[wr + mi * 16 + m16][ks * 32 + 8 * g];
      #pragma unroll
      for (int ni = 0; ni < 4; ++ni) bf4[ni] = *(const b16x8*)&Bt[wc + ni * 16 + m16][ks * 32 + 8 * g];
      #pragma unroll
      for (int mi = 0; mi < 4; ++mi)
        #pragma unroll
        for (int ni = 0; ni < 4; ++ni)
          acc[mi][ni] = MFMA(af[mi], bf4[ni], acc[mi][ni]);
    }
  }
  #pragma unroll
  for (int mi = 0; mi < 4; ++mi)
    #pragma unroll
    for (int ni = 0; ni < 4; ++ni) {
      int gcol = n0 + wc + ni * 16 + m16;
      #pragma unroll
      for (int r = 0; r < 4; ++r) {
        int grow = m0 + wr + mi * 16 + 4 * g + r;
        int bb = grow >> 9;
        float a = acc[mi][ni][r];
        if (gcol < 256) {
          float v = a + cz[bb * 256 + gcol];
          z[(size_t)grow * 256 + gcol] = (__bf16)(1.f / (1.f + __expf(-v)));
        } else {
          int c2 = gcol - 256;
          float v  = a + cr[bb * 256 + c2];
          float rr = 1.f / (1.f + __expf(-v));
          rh[(size_t)grow * 256 + c2] = (__bf16)(rr * h[(size_t)grow * 256 + c2]);
        }
      }
    }
}

// ---------------------------------------------------------------------------
// h_tilde = tanh([msg|r*h] @ WhcT^T + c_h);  out = (1-z)*h + z*h_tilde
// Grid (512 m-tiles, 2 n-tiles).
// ---------------------------------------------------------------------------
__global__ __launch_bounds__(256) void k_gemm_ht(
    const __bf16* __restrict__ msg, const __bf16* __restrict__ rh,
    const __bf16* __restrict__ WhcT, const float* __restrict__ ch,
    const __bf16* __restrict__ z, const float* __restrict__ h,
    float* __restrict__ out) {
  __shared__ __bf16 At[128][72], Bt[128][72];
  const int tid = threadIdx.x, lane = tid & 63, wave = tid >> 6;
  const int g = lane >> 4, m16 = lane & 15;
  const int wr = (wave >> 1) * 64, wc = (wave & 1) * 64;
  const int m0 = blockIdx.x * 128, n0 = blockIdx.y * 128;
  f32x4 acc[4][4] = {};
  for (int k0 = 0; k0 < 512; k0 += 64) {
    __syncthreads();
    const __bf16* asrc = (k0 < 256) ? msg : rh;
    int ak = k0 & 255;
    #pragma unroll
    for (int i = 0; i < 4; ++i) {
      int c = tid + i * 256;
      int row = c >> 3, kc = (c & 7) * 8;
      *(b16x8*)&At[row][kc] = *(const b16x8*)(asrc + (size_t)(m0 + row) * 256 + ak + kc);
      *(b16x8*)&Bt[row][kc] = *(const b16x8*)(WhcT + (size_t)(n0 + row) * 512 + k0 + kc);
    }
    __syncthreads();
    #pragma unroll
    for (int ks = 0; ks < 2; ++ks) {
      b16x8 af[4], bf4[4];
      #pragma unroll
      for (int mi = 0; mi < 4; ++mi) af[mi]  = *(const b16x8*)&At[wr + mi * 16 + m16][ks * 32 + 8 * g];
      #pragma unroll
      for (int ni = 0; ni < 4; ++ni) bf4[ni] = *(const b16x8*)&Bt[wc + ni * 16 + m16][ks * 32 + 8 * g];
      #pragma unroll
      for (int mi = 0; mi < 4; ++mi)
        #pragma unroll
        for (int ni = 0; ni < 4; ++ni)
          acc[mi][ni] = MFMA(af[mi], bf4[ni], acc[mi][ni]);
    }
  }
  #pragma unroll
  for (int mi = 0; mi < 4; ++mi)
    #pragma unroll
    for (int ni = 0; ni < 4; ++ni) {
      int gcol = n0 + wc + ni * 16 + m16;
      #pragma unroll
      for (int r = 0; r < 4; ++r) {
        int grow = m0 + wr + mi * 16 + 4 * g + r;
        int bb = grow >> 9;
        size_t oidx = (size_t)grow * 256 + gcol;
        float pre = acc[mi][ni][r] + ch[bb * 256 + gcol];
        float htl = tanhf(pre);
        float zv  = (float)z[oidx];
        float hv  = h[oidx];
        out[oidx] = (1.f - zv) * hv + zv * htl;
      }
    }
}

// ---------------------------------------------------------------------------
extern "C" void kernel_launch(void* const* d_in, const int* in_sizes, int n_in,
                              void* d_out, int out_size, void* d_ws, size_t ws_size,
                              hipStream_t stream) {
  const float* h    = (const float*)d_in[0];
  const float* jets = (const float*)d_in[1];
  const float* mask = (const float*)d_in[2];
  const float* Wa   = (const float*)d_in[3];
  const float* ba   = (const float*)d_in[4];
  const float* Wm   = (const float*)d_in[5];
  const float* bm   = (const float*)d_in[6];
  const float* Wz   = (const float*)d_in[7];
  const float* bz   = (const float*)d_in[8];
  const float* Wr   = (const float*)d_in[9];
  const float* br   = (const float*)d_in[10];
  const float* Wh   = (const float*)d_in[11];
  const float* bh   = (const float*)d_in[12];
  float* out = (float*)d_out;

  char* ws = (char*)d_ws;
  size_t off = 0;
  auto alloc = [&](size_t bytes) -> void* {
    void* p = ws + off;
    off += (bytes + 255) & ~(size_t)255;
    return p;
  };
  float*  q     = (float*) alloc((size_t)ROWS * H_ * 4);   // aliased by z/rh later
  __bf16* hmT   = (__bf16*)alloc((size_t)B_ * H_ * N_ * 2);
  __bf16* msg   = (__bf16*)alloc((size_t)ROWS * H_ * 2);
  float*  hmean = (float*) alloc((size_t)B_ * H_ * 4);
  float*  cz    = (float*) alloc((size_t)B_ * H_ * 4);
  float*  cr    = (float*) alloc((size_t)B_ * H_ * 4);
  float*  chv   = (float*) alloc((size_t)B_ * H_ * 4);
  __bf16* WaT_hi = (__bf16*)alloc(65536 * 2);
  __bf16* WaT_lo = (__bf16*)alloc(65536 * 2);
  __bf16* WmT    = (__bf16*)alloc(65536 * 2);
  __bf16* WzrT   = (__bf16*)alloc(262144 * 2);
  __bf16* WhcT   = (__bf16*)alloc(131072 * 2);
  // z and rh alias the q buffer: q is dead after attention.
  __bf16* z  = (__bf16*)q;
  __bf16* rh = (__bf16*)((char*)q + (size_t)ROWS * H_ * 2);
  if (off > ws_size) return;  // cannot run at all

  // K images (consumed only by k_attn2); graceful degradation if ws is tight.
  size_t kimg_bytes = (size_t)ROWS * H_ * 2;   // 33.5 MB each
  bool use_khi = (off + kimg_bytes) <= ws_size;
  __bf16* Khi = use_khi ? (__bf16*)alloc(kimg_bytes) : nullptr;
  bool use_klo = use_khi && (off + kimg_bytes) <= ws_size;
  __bf16* Klo = use_klo ? (__bf16*)alloc(kimg_bytes) : Khi;

  k_prep   <<<2048, 256, 0, stream>>>(Wa, Wm, Wz, Wr, Wh, WaT_hi, WaT_lo, WmT, WzrT, WhcT);
  k_hmean  <<<B_, H_, 0, stream>>>(h, hmean);
  k_cvec   <<<B_, H_, 0, stream>>>(hmean, jets, Wz, Wr, Wh, bz, br, bh, cz, cr, chv);
  if (use_khi)
    k_ksplit<<<8192, 256, 0, stream>>>(h, Khi, Klo, use_klo ? 1 : 0);
  k_gemm_q <<<dim3(512, 2), 256, 0, stream>>>(h, WaT_hi, WaT_lo, ba, q);
  k_gemm_hmT<<<dim3(128, 8), 256, 0, stream>>>(h, WmT, bm, hmT);
  if (use_khi) {
    if (use_klo) k_attn2<true> <<<dim3(128, 8), 256, 0, stream>>>(q, mask, hmT, Khi, Klo, msg);
    else         k_attn2<false><<<dim3(128, 8), 256, 0, stream>>>(q, mask, hmT, Khi, Khi, msg);
  } else {
    k_attn_fb<<<dim3(128, 8), 256, 0, stream>>>(q, h, mask, hmT, msg);
  }
  k_gemm_zr<<<dim3(512, 4), 256, 0, stream>>>(msg, h, WzrT, cz, cr, z, rh);
  k_gemm_ht<<<dim3(512, 2), 256, 0, stream>>>(msg, rh, WhcT, chv, z, h, out);
}

// Round 3
// 691.698 us; speedup vs baseline: 1.0220x; 1.0220x over previous
//
#include <hip/hip_runtime.h>

// Problem constants (from reference): B=128, N=512, H=256, F_JET=8, gin=776.
#define B_   128
#define N_   512
#define H_   256
#define FJ   8
#define ROWS (B_ * N_)          // 65536 flattened vertex rows
#define NEGV (-1e9f)

typedef _Float16 f16;
typedef __attribute__((ext_vector_type(8))) f16   f16x8;   // one MFMA A/B fragment (4 VGPRs)
typedef __attribute__((ext_vector_type(4))) float f32x4;   // one MFMA C/D fragment

static __device__ inline f32x4 MFMA16(f16x8 a, f16x8 b, f32x4 c) {
  return __builtin_amdgcn_mfma_f32_16x16x32_f16(a, b, c, 0, 0, 0);
}

// global -> LDS direct copy, 16B per lane. LDS ptr must be wave-uniform; HW adds lane*16.
static __device__ inline void gld16(const void* g, void* l) {
  __builtin_amdgcn_global_load_lds(
      (const __attribute__((address_space(1))) void*)g,
      (__attribute__((address_space(3))) void*)(uintptr_t)l,
      16, 0, 0);
}

// ---------------------------------------------------------------------------
// Prep: transpose/convert weights to fp16 once per launch.
//  WaT[d][k]  = f16(Wa[k][d])            (256x256)
//  WmT[d][k]  = f16(Wm[k][d])            (256x256)
//  WzrT[n][k] = f16(W{z|r}[row(k)][n'])  (512x512), n<256 -> Wz else Wr
//               row(k) = k<256 ? k : 520+(k-256)
//  WhcT[n][k] = f16(Wh[row(k)][n])       (256x512)
// ---------------------------------------------------------------------------
__global__ void k_prep(const float* __restrict__ Wa, const float* __restrict__ Wm,
                       const float* __restrict__ Wz, const float* __restrict__ Wr,
                       const float* __restrict__ Wh,
                       f16* __restrict__ WaT, f16* __restrict__ WmT,
                       f16* __restrict__ WzrT, f16* __restrict__ WhcT) {
  int idx = blockIdx.x * 256 + threadIdx.x;
  if (idx < 65536) {
    int d = idx >> 8, k = idx & 255;
    WaT[d * 256 + k] = (f16)Wa[k * 256 + d];
  } else if (idx < 131072) {
    int t = idx - 65536;
    int d = t >> 8, k = t & 255;
    WmT[d * 256 + k] = (f16)Wm[k * 256 + d];
  } else if (idx < 131072 + 262144) {
    int t = idx - 131072;
    int n = t >> 9, k = t & 511;
    const float* src = (n < 256) ? Wz : Wr;
    int np  = n & 255;
    int row = (k < 256) ? k : (264 + k);   // 520 + (k - 256)
    WzrT[n * 512 + k] = (f16)src[row * 256 + np];
  } else {
    int t = idx - (131072 + 262144);       // < 131072
    int n = t >> 9, k = t & 511;
    int row = (k < 256) ? k : (264 + k);
    WhcT[n * 512 + k] = (f16)Wh[row * 256 + n];
  }
}

// h_mean[b][d] = mean_n h[b][n][d]
__global__ void k_hmean(const float* __restrict__ h, float* __restrict__ hmean) {
  int b = blockIdx.x, d = threadIdx.x;
  const float* p = h + (size_t)b * N_ * H_ + d;
  float s = 0.f;
  #pragma unroll 8
  for (int n = 0; n < N_; ++n) s += p[n * H_];
  hmean[b * H_ + d] = s * (1.f / N_);
}

// Per-batch GRU constants: c_*[b][d] = bias[d] + h_mean[b]·W*[256:512,d] + jets[b]·W*[512:520,d]
__global__ void k_cvec(const float* __restrict__ hmean, const float* __restrict__ jets,
                       const float* __restrict__ Wz, const float* __restrict__ Wr,
                       const float* __restrict__ Wh,
                       const float* __restrict__ bz, const float* __restrict__ br,
                       const float* __restrict__ bh,
                       float* __restrict__ cz, float* __restrict__ cr, float* __restrict__ ch) {
  __shared__ float hm[H_];
  __shared__ float jt[FJ];
  int b = blockIdx.x, d = threadIdx.x;
  hm[d] = hmean[b * H_ + d];
  if (d < FJ) jt[d] = jets[b * FJ + d];
  __syncthreads();
  float az = bz[d], ar = br[d], ah = bh[d];
  #pragma unroll 4
  for (int k = 0; k < H_; ++k) {
    float m = hm[k];
    az += m * Wz[(256 + k) * 256 + d];
    ar += m * Wr[(256 + k) * 256 + d];
    ah += m * Wh[(256 + k) * 256 + d];
  }
  #pragma unroll
  for (int f = 0; f < FJ; ++f) {
    float j = jt[f];
    az += j * Wz[(512 + f) * 256 + d];
    ar += j * Wr[(512 + f) * 256 + d];
    ah += j * Wh[(512 + f) * 256 + d];
  }
  cz[b * H_ + d] = az;
  cr[b * H_ + d] = ar;
  ch[b * H_ + d] = ah;
}

// ---------------------------------------------------------------------------
// K image: fp16 copy of h, pre-swizzled per row for the attn LDS read pattern:
// row j holds 32 16B-chunks; chunk c (elems k=c*8..c*8+7) stored at slot c^(j&7).
// ---------------------------------------------------------------------------
__global__ void k_kimg(const float* __restrict__ h, f16* __restrict__ Kimg) {
  int t  = blockIdx.x * 256 + threadIdx.x;   // chunk id: 128*512*32 = 2,097,152
  int c  = t & 31;
  int rj = t >> 5;                            // b*512 + j
  const float* p = h + (size_t)rj * 256 + c * 8;
  f32x4 v0 = *(const f32x4*)p;
  f32x4 v1 = *(const f32x4*)(p + 4);
  f16x8 hv;
  #pragma unroll
  for (int e = 0; e < 4; ++e) { hv[e] = (f16)v0[e]; hv[4 + e] = (f16)v1[e]; }
  *(f16x8*)&Kimg[(size_t)rj * 256 + (size_t)((c ^ (rj & 7)) * 8)] = hv;
}

// ---------------------------------------------------------------------------
// q = f16(h @ Wa + ba), single-term fp16, BK=64. Grid (512 m-tiles, 2 n-tiles).
// ---------------------------------------------------------------------------
__global__ __launch_bounds__(256) void k_gemm_q(
    const float* __restrict__ h, const f16* __restrict__ WaT,
    const float* __restrict__ ba, f16* __restrict__ q) {
  __shared__ __align__(16) f16 At[128][72], Bt[128][72];
  const int tid = threadIdx.x, lane = tid & 63, wave = tid >> 6;
  const int g = lane >> 4, m16 = lane & 15;
  const int wr = (wave >> 1) * 64, wc = (wave & 1) * 64;
  const int m0 = blockIdx.x * 128, n0 = blockIdx.y * 128;
  f32x4 acc[4][4] = {};
  for (int k0 = 0; k0 < 256; k0 += 64) {
    __syncthreads();
    #pragma unroll
    for (int i = 0; i < 4; ++i) {
      int c = tid + i * 256;                // 1024 chunks of 8
      int row = c >> 3, kc = (c & 7) * 8;
      const float* p = h + (size_t)(m0 + row) * 256 + k0 + kc;
      f32x4 v0 = *(const f32x4*)p, v1 = *(const f32x4*)(p + 4);
      f16x8 hv;
      #pragma unroll
      for (int e = 0; e < 4; ++e) { hv[e] = (f16)v0[e]; hv[4 + e] = (f16)v1[e]; }
      *(f16x8*)&At[row][kc] = hv;
      *(f16x8*)&Bt[row][kc] = *(const f16x8*)(WaT + (size_t)(n0 + row) * 256 + k0 + kc);
    }
    __syncthreads();
    #pragma unroll
    for (int ks = 0; ks < 2; ++ks) {
      f16x8 af[4], bf4[4];
      #pragma unroll
      for (int mi = 0; mi < 4; ++mi) af[mi]  = *(const f16x8*)&At[wr + mi * 16 + m16][ks * 32 + 8 * g];
      #pragma unroll
      for (int ni = 0; ni < 4; ++ni) bf4[ni] = *(const f16x8*)&Bt[wc + ni * 16 + m16][ks * 32 + 8 * g];
      #pragma unroll
      for (int mi = 0; mi < 4; ++mi)
        #pragma unroll
        for (int ni = 0; ni < 4; ++ni)
          acc[mi][ni] = MFMA16(af[mi], bf4[ni], acc[mi][ni]);
    }
  }
  #pragma unroll
  for (int mi = 0; mi < 4; ++mi)
    #pragma unroll
    for (int ni = 0; ni < 4; ++ni) {
      int gcol = n0 + wc + ni * 16 + m16;
      float bias = ba[gcol];
      #pragma unroll
      for (int r = 0; r < 4; ++r) {
        int grow = m0 + wr + mi * 16 + 4 * g + r;
        q[(size_t)grow * 256 + gcol] = (f16)(acc[mi][ni][r] + bias);
      }
    }
}

// ---------------------------------------------------------------------------
// hmT[b][d][n] = f16( (h[b] @ Wm + bm)^T ). Grid (128 batches, 8 tiles).
// ---------------------------------------------------------------------------
__global__ __launch_bounds__(256) void k_gemm_hmT(
    const float* __restrict__ h, const f16* __restrict__ WmT,
    const float* __restrict__ bm, f16* __restrict__ hmT) {
  __shared__ __align__(16) f16 At[128][72], Bt[128][72];
  const int tid = threadIdx.x, lane = tid & 63, wave = tid >> 6;
  const int g = lane >> 4, m16 = lane & 15;
  const int wr = (wave >> 1) * 64, wc = (wave & 1) * 64;
  const int b = blockIdx.x;
  const int m0 = (blockIdx.y >> 2) * 128, n0 = (blockIdx.y & 3) * 128;
  const float* hb = h + (size_t)b * N_ * H_;
  f32x4 acc[4][4] = {};
  for (int k0 = 0; k0 < 256; k0 += 64) {
    __syncthreads();
    #pragma unroll
    for (int i = 0; i < 4; ++i) {
      int c = tid + i * 256;                // 1024 chunks of 8
      int row = c >> 3, kc = (c & 7) * 8;
      *(f16x8*)&At[row][kc] = *(const f16x8*)(WmT + (size_t)(m0 + row) * 256 + k0 + kc);
      const float* p = hb + (size_t)(n0 + row) * 256 + k0 + kc;
      f32x4 v0 = *(const f32x4*)p, v1 = *(const f32x4*)(p + 4);
      f16x8 hv;
      #pragma unroll
      for (int e = 0; e < 4; ++e) { hv[e] = (f16)v0[e]; hv[4 + e] = (f16)v1[e]; }
      *(f16x8*)&Bt[row][kc] = hv;
    }
    __syncthreads();
    #pragma unroll
    for (int ks = 0; ks < 2; ++ks) {
      f16x8 af[4], bf4[4];
      #pragma unroll
      for (int mi = 0; mi < 4; ++mi) af[mi]  = *(const f16x8*)&At[wr + mi * 16 + m16][ks * 32 + 8 * g];
      #pragma unroll
      for (int ni = 0; ni < 4; ++ni) bf4[ni] = *(const f16x8*)&Bt[wc + ni * 16 + m16][ks * 32 + 8 * g];
      #pragma unroll
      for (int mi = 0; mi < 4; ++mi)
        #pragma unroll
        for (int ni = 0; ni < 4; ++ni)
          acc[mi][ni] = MFMA16(af[mi], bf4[ni], acc[mi][ni]);
    }
  }
  #pragma unroll
  for (int mi = 0; mi < 4; ++mi)
    #pragma unroll
    for (int r = 0; r < 4; ++r) {
      int d = m0 + wr + mi * 16 + 4 * g + r;
      float bias = bm[d];
      #pragma unroll
      for (int ni = 0; ni < 4; ++ni) {
        int n = n0 + wc + ni * 16 + m16;
        hmT[(size_t)b * H_ * N_ + (size_t)d * N_ + n] = (f16)(acc[mi][ni][r] + bias);
      }
    }
}

// ---------------------------------------------------------------------------
// Flash attention + DTNN message, v3 (fp16, KVBLK=64):
//   msg[b,i,:] = tanh( mask_i * softmax_j(q_i·h_j + NEG*(1-mask_j)) @ hm )
// Block = (64 i-rows, batch b); 4 waves x 16 rows; 8 j-tiles of 64 with online
// softmax; K staged double-buffered via global_load_lds from the pre-swizzled
// fp16 image; mask cached in LDS; V frags straight from hmT (L2-hot).
// ---------------------------------------------------------------------------
__global__ __launch_bounds__(256) void k_attn3(
    const f16* __restrict__ q, const float* __restrict__ mask,
    const f16* __restrict__ hmT, const f16* __restrict__ Kimg,
    f16* __restrict__ msg) {
  __shared__ __align__(16) f16 KB[2][64 * 256];   // 2 x 32KB double buffer
  __shared__ __align__(16) f16 Plds[4][16][72];
  __shared__ float mask_lds[N_];
  const int tid = threadIdx.x, lane = tid & 63, wave = tid >> 6;
  const int g = lane >> 4, m16 = lane & 15;
  const int b = blockIdx.x, i0 = blockIdx.y * 64;

  mask_lds[tid]       = mask[b * N_ + tid];
  mask_lds[tid + 256] = mask[b * N_ + tid + 256];

  // Q fragments (fp16, rows i0 + wave*16 + m16)
  const f16* qp = q + (size_t)(b * N_ + i0 + wave * 16 + m16) * H_ + 8 * g;
  f16x8 qf[8];
  #pragma unroll
  for (int kb = 0; kb < 8; ++kb) qf[kb] = *(const f16x8*)(qp + kb * 32);

  f32x4 o[16] = {};
  float mrun[4], lrun[4];
  #pragma unroll
  for (int r = 0; r < 4; ++r) { mrun[r] = -3.0e38f; lrun[r] = 0.f; }

  const f16* hvb = hmT + (size_t)b * H_ * N_;
  const char* ksrc = (const char*)(Kimg + (size_t)b * N_ * H_);

  auto stage = [&](int jt, int buf) {
    const char* s = ksrc + jt * 32768 + wave * 8192 + lane * 16;
    char* l = (char*)&KB[buf][0] + wave * 8192;
    #pragma unroll
    for (int i = 0; i < 8; ++i) gld16(s + i * 1024, l + i * 1024);
  };

  stage(0, 0);
  asm volatile("s_waitcnt vmcnt(0)" ::: "memory");
  __syncthreads();

  for (int jt = 0; jt < 8; ++jt) {
    const int cur = jt & 1, j0 = jt * 64;
    if (jt < 7) stage(jt + 1, cur ^ 1);

    // S = q·K^T: 16 rows x 64 cols per wave, XOR-deswizzled K reads
    f32x4 s[4] = {};
    #pragma unroll
    for (int kb = 0; kb < 8; ++kb)
      #pragma unroll
      for (int cf = 0; cf < 4; ++cf) {
        const int jr = cf * 16 + m16;
        f16x8 kf = *(const f16x8*)&KB[cur][jr * 256 + (((kb * 4 + g) ^ (m16 & 7)) << 3)];
        s[cf] = MFMA16(qf[kb], kf, s[cf]);
      }
    // column mask
    #pragma unroll
    for (int cf = 0; cf < 4; ++cf) {
      float cm  = mask_lds[j0 + cf * 16 + m16];
      float add = NEGV * (1.f - cm);
      #pragma unroll
      for (int r = 0; r < 4; ++r) s[cf][r] += add;
    }
    // online softmax (rows live in 16-lane groups)
    float p_[4][4];
    #pragma unroll
    for (int r = 0; r < 4; ++r) {
      float mx = fmaxf(fmaxf(s[0][r], s[1][r]), fmaxf(s[2][r], s[3][r]));
      #pragma unroll
      for (int off = 1; off < 16; off <<= 1) mx = fmaxf(mx, __shfl_xor(mx, off, 64));
      float mnew  = fmaxf(mrun[r], mx);
      float alpha = __expf(mrun[r] - mnew);
      float ps = 0.f;
      #pragma unroll
      for (int cf = 0; cf < 4; ++cf) {
        float pv = __expf(s[cf][r] - mnew);
        p_[cf][r] = pv; ps += pv;
      }
      #pragma unroll
      for (int off = 1; off < 16; off <<= 1) ps += __shfl_xor(ps, off, 64);
      lrun[r] = lrun[r] * alpha + ps;
      mrun[r] = mnew;
      #pragma unroll
      for (int c2 = 0; c2 < 16; ++c2) o[c2][r] *= alpha;
    }
    // P -> LDS (C-layout) -> A-fragment layout (wave-local round trip)
    #pragma unroll
    for (int cf = 0; cf < 4; ++cf)
      #pragma unroll
      for (int r = 0; r < 4; ++r)
        Plds[wave][4 * g + r][cf * 16 + m16] = (f16)p_[cf][r];
    asm volatile("s_waitcnt lgkmcnt(0)" ::: "memory");
    __builtin_amdgcn_sched_barrier(0);
    f16x8 pa[2];
    #pragma unroll
    for (int ks = 0; ks < 2; ++ks) pa[ks] = *(const f16x8*)&Plds[wave][m16][ks * 32 + 8 * g];
    // PV: o += P @ hm_tile (B-frags straight from hmT, k-contiguous, L2-hot)
    #pragma unroll
    for (int c2 = 0; c2 < 16; ++c2) {
      const f16* vp = hvb + (size_t)(c2 * 16 + m16) * N_ + j0 + 8 * g;
      f16x8 v0 = *(const f16x8*)vp;
      f16x8 v1 = *(const f16x8*)(vp + 32);
      o[c2] = MFMA16(pa[0], v0, o[c2]);
      o[c2] = MFMA16(pa[1], v1, o[c2]);
    }
    asm volatile("s_waitcnt vmcnt(0)" ::: "memory");
    __syncthreads();
  }

  // epilogue: msg = tanh(row_mask * O / l)
  #pragma unroll
  for (int r = 0; r < 4; ++r) {
    int irow = i0 + wave * 16 + 4 * g + r;
    float rm  = mask_lds[irow];
    float inv = rm / lrun[r];
    #pragma unroll
    for (int c2 = 0; c2 < 16; ++c2) {
      float val = tanhf(o[c2][r] * inv);
      msg[(size_t)(b * N_ + irow) * H_ + c2 * 16 + m16] = (f16)val;
    }
  }
}

// ---------------------------------------------------------------------------
// Gates: [z|r]_pre = [msg|h] @ WzrT^T + c_{z|r};  z = sigmoid, rh = sigmoid(r)*h
// Grid (512 m-tiles, 4 n-tiles).
// ---------------------------------------------------------------------------
__global__ __launch_bounds__(256) void k_gemm_zr(
    const f16* __restrict__ msg, const float* __restrict__ h,
    const f16* __restrict__ WzrT, const float* __restrict__ cz,
    const float* __restrict__ cr, f16* __restrict__ z, f16* __restrict__ rh) {
  __shared__ __align__(16) f16 At[128][72], Bt[128][72];
  const int tid = threadIdx.x, lane = tid & 63, wave = tid >> 6;
  const int g = lane >> 4, m16 = lane & 15;
  const int wr = (wave >> 1) * 64, wc = (wave & 1) * 64;
  const int m0 = blockIdx.x * 128, n0 = blockIdx.y * 128;
  f32x4 acc[4][4] = {};
  for (int k0 = 0; k0 < 512; k0 += 64) {
    __syncthreads();
    #pragma unroll
    for (int i = 0; i < 4; ++i) {
      int c = tid + i * 256;
      int row = c >> 3, kc = (c & 7) * 8;
      if (k0 < 256) {
        *(f16x8*)&At[row][kc] = *(const f16x8*)(msg + (size_t)(m0 + row) * 256 + k0 + kc);
      } else {
        const float* p = h + (size_t)(m0 + row) * 256 + (k0 - 256) + kc;
        f32x4 v0 = *(const f32x4*)p, v1 = *(const f32x4*)(p + 4);
        f16x8 hv;
        #pragma unroll
        for (int e = 0; e < 4; ++e) { hv[e] = (f16)v0[e]; hv[4 + e] = (f16)v1[e]; }
        *(f16x8*)&At[row][kc] = hv;
      }
      *(f16x8*)&Bt[row][kc] = *(const f16x8*)(WzrT + (size_t)(n0 + row) * 512 + k0 + kc);
    }
    __syncthreads();
    #pragma unroll
    for (int ks = 0; ks < 2; ++ks) {
      f16x8 af[4], bf4[4];
      #pragma unroll
      for (int mi = 0; mi < 4; ++mi) af[mi]  = *(const f16x8*)&At[wr + mi * 16 + m16][ks * 32 + 8 * g];
      #pragma unroll
      for (int ni = 0; ni < 4; ++ni) bf4[ni] = *(const f16x8*)&Bt[wc + ni * 16 + m16][ks * 32 + 8 * g];
      #pragma unroll
      for (int mi = 0; mi < 4; ++mi)
        #pragma unroll
        for (int ni = 0; ni < 4; ++ni)
          acc[mi][ni] = MFMA16(af[mi], bf4[ni], acc[mi][ni]);
    }
  }
  #pragma unroll
  for (int mi = 0; mi < 4; ++mi)
    #pragma unroll
    for (int ni = 0; ni < 4; ++ni) {
      int gcol = n0 + wc + ni * 16 + m16;
      #pragma unroll
      for (int r = 0; r < 4; ++r) {
        int grow = m0 + wr + mi * 16 + 4 * g + r;
        int bb = grow >> 9;
        float a = acc[mi][ni][r];
        if (gcol < 256) {
          float v = a + cz[bb * 256 + gcol];
          z[(size_t)grow * 256 + gcol] = (f16)(1.f / (1.f + __expf(-v)));
        } else {
          int c2 = gcol - 256;
          float v  = a + cr[bb * 256 + c2];
          float rr = 1.f / (1.f + __expf(-v));
          rh[(size_t)grow * 256 + c2] = (f16)(rr * h[(size_t)grow * 256 + c2]);
        }
      }
    }
}

// ---------------------------------------------------------------------------
// h_tilde = tanh([msg|r*h] @ WhcT^T + c_h);  out = (1-z)*h + z*h_tilde
// Grid (512 m-tiles, 2 n-tiles).
// ---------------------------------------------------------------------------
__global__ __launch_bounds__(256) void k_gemm_ht(
    const f16* __restrict__ msg, const f16* __restrict__ rh,
    const f16* __restrict__ WhcT, const float* __restrict__ ch,
    const f16* __restrict__ z, const float* __restrict__ h,
    float* __restrict__ out) {
  __shared__ __align__(16) f16 At[128][72], Bt[128][72];
  const int tid = threadIdx.x, lane = tid & 63, wave = tid >> 6;
  const int g = lane >> 4, m16 = lane & 15;
  const int wr = (wave >> 1) * 64, wc = (wave & 1) * 64;
  const int m0 = blockIdx.x * 128, n0 = blockIdx.y * 128;
  f32x4 acc[4][4] = {};
  for (int k0 = 0; k0 < 512; k0 += 64) {
    __syncthreads();
    const f16* asrc = (k0 < 256) ? msg : rh;
    int ak = k0 & 255;
    #pragma unroll
    for (int i = 0; i < 4; ++i) {
      int c = tid + i * 256;
      int row = c >> 3, kc = (c & 7) * 8;
      *(f16x8*)&At[row][kc] = *(const f16x8*)(asrc + (size_t)(m0 + row) * 256 + ak + kc);
      *(f16x8*)&Bt[row][kc] = *(const f16x8*)(WhcT + (size_t)(n0 + row) * 512 + k0 + kc);
    }
    __syncthreads();
    #pragma unroll
    for (int ks = 0; ks < 2; ++ks) {
      f16x8 af[4], bf4[4];
      #pragma unroll
      for (int mi = 0; mi < 4; ++mi) af[mi]  = *(const f16x8*)&At[wr + mi * 16 + m16][ks * 32 + 8 * g];
      #pragma unroll
      for (int ni = 0; ni < 4; ++ni) bf4[ni] = *(const f16x8*)&Bt[wc + ni * 16 + m16][ks * 32 + 8 * g];
      #pragma unroll
      for (int mi = 0; mi < 4; ++mi)
        #pragma unroll
        for (int ni = 0; ni < 4; ++ni)
          acc[mi][ni] = MFMA16(af[mi], bf4[ni], acc[mi][ni]);
    }
  }
  #pragma unroll
  for (int mi = 0; mi < 4; ++mi)
    #pragma unroll
    for (int ni = 0; ni < 4; ++ni) {
      int gcol = n0 + wc + ni * 16 + m16;
      #pragma unroll
      for (int r = 0; r < 4; ++r) {
        int grow = m0 + wr + mi * 16 + 4 * g + r;
        int bb = grow >> 9;
        size_t oidx = (size_t)grow * 256 + gcol;
        float pre = acc[mi][ni][r] + ch[bb * 256 + gcol];
        float htl = tanhf(pre);
        float zv  = (float)z[oidx];
        float hv  = h[oidx];
        out[oidx] = (1.f - zv) * hv + zv * htl;
      }
    }
}

// ---------------------------------------------------------------------------
extern "C" void kernel_launch(void* const* d_in, const int* in_sizes, int n_in,
                              void* d_out, int out_size, void* d_ws, size_t ws_size,
                              hipStream_t stream) {
  const float* h    = (const float*)d_in[0];
  const float* jets = (const float*)d_in[1];
  const float* mask = (const float*)d_in[2];
  const float* Wa   = (const float*)d_in[3];
  const float* ba   = (const float*)d_in[4];
  const float* Wm   = (const float*)d_in[5];
  const float* bm   = (const float*)d_in[6];
  const float* Wz   = (const float*)d_in[7];
  const float* bz   = (const float*)d_in[8];
  const float* Wr   = (const float*)d_in[9];
  const float* br   = (const float*)d_in[10];
  const float* Wh   = (const float*)d_in[11];
  const float* bh   = (const float*)d_in[12];
  float* out = (float*)d_out;

  char* ws = (char*)d_ws;
  size_t off = 0;
  auto alloc = [&](size_t bytes) -> void* {
    void* p = ws + off;
    off += (bytes + 255) & ~(size_t)255;
    return p;
  };
  // big: q (f16, 32MB) during attention; z (f16) + rh (f16) afterwards.
  char*   big   = (char*) alloc((size_t)ROWS * H_ * 4);
  f16*    hmT   = (f16*)  alloc((size_t)B_ * H_ * N_ * 2);
  f16*    msg   = (f16*)  alloc((size_t)ROWS * H_ * 2);
  f16*    Kimg  = (f16*)  alloc((size_t)ROWS * H_ * 2);
  float*  hmean = (float*)alloc((size_t)B_ * H_ * 4);
  float*  cz    = (float*)alloc((size_t)B_ * H_ * 4);
  float*  cr    = (float*)alloc((size_t)B_ * H_ * 4);
  float*  chv   = (float*)alloc((size_t)B_ * H_ * 4);
  f16*    WaT   = (f16*)  alloc(65536 * 2);
  f16*    WmT   = (f16*)  alloc(65536 * 2);
  f16*    WzrT  = (f16*)  alloc(262144 * 2);
  f16*    WhcT  = (f16*)  alloc(131072 * 2);
  f16* q  = (f16*)big;
  f16* z  = (f16*)big;                                     // q dead after attn
  f16* rh = (f16*)(big + (size_t)ROWS * H_ * 2);
  if (off > ws_size) return;  // workspace insufficient

  k_prep    <<<2048, 256, 0, stream>>>(Wa, Wm, Wz, Wr, Wh, WaT, WmT, WzrT, WhcT);
  k_hmean   <<<B_, H_, 0, stream>>>(h, hmean);
  k_cvec    <<<B_, H_, 0, stream>>>(hmean, jets, Wz, Wr, Wh, bz, br, bh, cz, cr, chv);
  k_kimg    <<<8192, 256, 0, stream>>>(h, Kimg);
  k_gemm_q  <<<dim3(512, 2), 256, 0, stream>>>(h, WaT, ba, q);
  k_gemm_hmT<<<dim3(128, 8), 256, 0, stream>>>(h, WmT, bm, hmT);
  k_attn3   <<<dim3(128, 8), 256, 0, stream>>>(q, mask, hmT, Kimg, msg);
  k_gemm_zr <<<dim3(512, 4), 256, 0, stream>>>(msg, h, WzrT, cz, cr, z, rh);
  k_gemm_ht <<<dim3(512, 2), 256, 0, stream>>>(msg, rh, WhcT, chv, z, h, out);
}

// Round 4
// 538.324 us; speedup vs baseline: 1.3132x; 1.2849x over previous
//
#include <hip/hip_runtime.h>

// Problem constants (from reference): B=128, N=512, H=256, F_JET=8, gin=776.
#define B_   128
#define N_   512
#define H_   256
#define FJ   8
#define ROWS (B_ * N_)          // 65536 flattened vertex rows
#define NEGV (-1e9f)

typedef _Float16 f16;
typedef __attribute__((ext_vector_type(8))) f16   f16x8;   // one MFMA A/B fragment (4 VGPRs)
typedef __attribute__((ext_vector_type(4))) float f32x4;   // one MFMA C/D fragment

static __device__ inline f32x4 MFMA16(f16x8 a, f16x8 b, f32x4 c) {
  return __builtin_amdgcn_mfma_f32_16x16x32_f16(a, b, c, 0, 0, 0);
}

// global -> LDS direct copy, 16B per lane. LDS ptr must be wave-uniform; HW adds lane*16.
static __device__ inline void gld16(const void* g, void* l) {
  __builtin_amdgcn_global_load_lds(
      (const __attribute__((address_space(1))) void*)g,
      (__attribute__((address_space(3))) void*)(uintptr_t)l,
      16, 0, 0);
}

// ---------------------------------------------------------------------------
// Prep: transpose/convert weights to fp16 once per launch.
// ---------------------------------------------------------------------------
__global__ void k_prep(const float* __restrict__ Wa, const float* __restrict__ Wm,
                       const float* __restrict__ Wz, const float* __restrict__ Wr,
                       const float* __restrict__ Wh,
                       f16* __restrict__ WaT, f16* __restrict__ WmT,
                       f16* __restrict__ WzrT, f16* __restrict__ WhcT) {
  int idx = blockIdx.x * 256 + threadIdx.x;
  if (idx < 65536) {
    int d = idx >> 8, k = idx & 255;
    WaT[d * 256 + k] = (f16)Wa[k * 256 + d];
  } else if (idx < 131072) {
    int t = idx - 65536;
    int d = t >> 8, k = t & 255;
    WmT[d * 256 + k] = (f16)Wm[k * 256 + d];
  } else if (idx < 131072 + 262144) {
    int t = idx - 131072;
    int n = t >> 9, k = t & 511;
    const float* src = (n < 256) ? Wz : Wr;
    int np  = n & 255;
    int row = (k < 256) ? k : (264 + k);   // 520 + (k - 256)
    WzrT[n * 512 + k] = (f16)src[row * 256 + np];
  } else {
    int t = idx - (131072 + 262144);       // < 131072
    int n = t >> 9, k = t & 511;
    int row = (k < 256) ? k : (264 + k);
    WhcT[n * 512 + k] = (f16)Wh[row * 256 + n];
  }
}

// partial sums: hmean4[b][part][d] = sum_{n in part} h[b][n][d], part of 128 rows
__global__ void k_hmean(const float* __restrict__ h, float* __restrict__ hmean4) {
  int b = blockIdx.x, part = blockIdx.y, d = threadIdx.x;
  const float* p = h + ((size_t)b * N_ + part * 128) * H_ + d;
  float s = 0.f;
  #pragma unroll 8
  for (int n = 0; n < 128; ++n) s += p[n * H_];
  hmean4[(b * 4 + part) * H_ + d] = s;
}

// Per-batch GRU constants: c_*[b][d] = bias[d] + h_mean[b]·W*[256:512,d] + jets[b]·W*[512:520,d]
__global__ void k_cvec(const float* __restrict__ hmean4, const float* __restrict__ jets,
                       const float* __restrict__ Wz, const float* __restrict__ Wr,
                       const float* __restrict__ Wh,
                       const float* __restrict__ bz, const float* __restrict__ br,
                       const float* __restrict__ bh,
                       float* __restrict__ cz, float* __restrict__ cr, float* __restrict__ ch) {
  __shared__ float hm[H_];
  __shared__ float jt[FJ];
  int b = blockIdx.x, d = threadIdx.x;
  hm[d] = (hmean4[(b * 4 + 0) * H_ + d] + hmean4[(b * 4 + 1) * H_ + d] +
           hmean4[(b * 4 + 2) * H_ + d] + hmean4[(b * 4 + 3) * H_ + d]) * (1.f / N_);
  if (d < FJ) jt[d] = jets[b * FJ + d];
  __syncthreads();
  float az = bz[d], ar = br[d], ah = bh[d];
  #pragma unroll 4
  for (int k = 0; k < H_; ++k) {
    float m = hm[k];
    az += m * Wz[(256 + k) * 256 + d];
    ar += m * Wr[(256 + k) * 256 + d];
    ah += m * Wh[(256 + k) * 256 + d];
  }
  #pragma unroll
  for (int f = 0; f < FJ; ++f) {
    float j = jt[f];
    az += j * Wz[(512 + f) * 256 + d];
    ar += j * Wr[(512 + f) * 256 + d];
    ah += j * Wh[(512 + f) * 256 + d];
  }
  cz[b * H_ + d] = az;
  cr[b * H_ + d] = ar;
  ch[b * H_ + d] = ah;
}

// ---------------------------------------------------------------------------
// K image: fp16 copy of h, pre-swizzled per row for the attn LDS read pattern:
// row j holds 32 16B-chunks; chunk c stored at slot c^(j&7).
// ---------------------------------------------------------------------------
__global__ void k_kimg(const float* __restrict__ h, f16* __restrict__ Kimg) {
  int t  = blockIdx.x * 256 + threadIdx.x;   // chunk id: 128*512*32 = 2,097,152
  int c  = t & 31;
  int rj = t >> 5;                            // b*512 + j
  const float* p = h + (size_t)rj * 256 + c * 8;
  f32x4 v0 = *(const f32x4*)p;
  f32x4 v1 = *(const f32x4*)(p + 4);
  f16x8 hv;
  #pragma unroll
  for (int e = 0; e < 4; ++e) { hv[e] = (f16)v0[e]; hv[4 + e] = (f16)v1[e]; }
  *(f16x8*)&Kimg[(size_t)rj * 256 + (size_t)((c ^ (rj & 7)) * 8)] = hv;
}

// ---------------------------------------------------------------------------
// q = f16(h @ Wa + ba), single-term fp16, BK=64. Grid (512 m-tiles, 2 n-tiles).
// ---------------------------------------------------------------------------
__global__ __launch_bounds__(256) void k_gemm_q(
    const float* __restrict__ h, const f16* __restrict__ WaT,
    const float* __restrict__ ba, f16* __restrict__ q) {
  __shared__ __align__(16) f16 At[128][72], Bt[128][72];
  const int tid = threadIdx.x, lane = tid & 63, wave = tid >> 6;
  const int g = lane >> 4, m16 = lane & 15;
  const int wr = (wave >> 1) * 64, wc = (wave & 1) * 64;
  const int m0 = blockIdx.x * 128, n0 = blockIdx.y * 128;
  f32x4 acc[4][4] = {};
  for (int k0 = 0; k0 < 256; k0 += 64) {
    __syncthreads();
    #pragma unroll
    for (int i = 0; i < 4; ++i) {
      int c = tid + i * 256;                // 1024 chunks of 8
      int row = c >> 3, kc = (c & 7) * 8;
      const float* p = h + (size_t)(m0 + row) * 256 + k0 + kc;
      f32x4 v0 = *(const f32x4*)p, v1 = *(const f32x4*)(p + 4);
      f16x8 hv;
      #pragma unroll
      for (int e = 0; e < 4; ++e) { hv[e] = (f16)v0[e]; hv[4 + e] = (f16)v1[e]; }
      *(f16x8*)&At[row][kc] = hv;
      *(f16x8*)&Bt[row][kc] = *(const f16x8*)(WaT + (size_t)(n0 + row) * 256 + k0 + kc);
    }
    __syncthreads();
    #pragma unroll
    for (int ks = 0; ks < 2; ++ks) {
      f16x8 af[4], bf4[4];
      #pragma unroll
      for (int mi = 0; mi < 4; ++mi) af[mi]  = *(const f16x8*)&At[wr + mi * 16 + m16][ks * 32 + 8 * g];
      #pragma unroll
      for (int ni = 0; ni < 4; ++ni) bf4[ni] = *(const f16x8*)&Bt[wc + ni * 16 + m16][ks * 32 + 8 * g];
      #pragma unroll
      for (int mi = 0; mi < 4; ++mi)
        #pragma unroll
        for (int ni = 0; ni < 4; ++ni)
          acc[mi][ni] = MFMA16(af[mi], bf4[ni], acc[mi][ni]);
    }
  }
  #pragma unroll
  for (int mi = 0; mi < 4; ++mi)
    #pragma unroll
    for (int ni = 0; ni < 4; ++ni) {
      int gcol = n0 + wc + ni * 16 + m16;
      float bias = ba[gcol];
      #pragma unroll
      for (int r = 0; r < 4; ++r) {
        int grow = m0 + wr + mi * 16 + 4 * g + r;
        q[(size_t)grow * 256 + gcol] = (f16)(acc[mi][ni][r] + bias);
      }
    }
}

// ---------------------------------------------------------------------------
// hmT[b][d][n] = f16( (h[b] @ Wm + bm)^T ). Grid (128 batches, 8 tiles).
// ---------------------------------------------------------------------------
__global__ __launch_bounds__(256) void k_gemm_hmT(
    const float* __restrict__ h, const f16* __restrict__ WmT,
    const float* __restrict__ bm, f16* __restrict__ hmT) {
  __shared__ __align__(16) f16 At[128][72], Bt[128][72];
  const int tid = threadIdx.x, lane = tid & 63, wave = tid >> 6;
  const int g = lane >> 4, m16 = lane & 15;
  const int wr = (wave >> 1) * 64, wc = (wave & 1) * 64;
  const int b = blockIdx.x;
  const int m0 = (blockIdx.y >> 2) * 128, n0 = (blockIdx.y & 3) * 128;
  const float* hb = h + (size_t)b * N_ * H_;
  f32x4 acc[4][4] = {};
  for (int k0 = 0; k0 < 256; k0 += 64) {
    __syncthreads();
    #pragma unroll
    for (int i = 0; i < 4; ++i) {
      int c = tid + i * 256;                // 1024 chunks of 8
      int row = c >> 3, kc = (c & 7) * 8;
      *(f16x8*)&At[row][kc] = *(const f16x8*)(WmT + (size_t)(m0 + row) * 256 + k0 + kc);
      const float* p = hb + (size_t)(n0 + row) * 256 + k0 + kc;
      f32x4 v0 = *(const f32x4*)p, v1 = *(const f32x4*)(p + 4);
      f16x8 hv;
      #pragma unroll
      for (int e = 0; e < 4; ++e) { hv[e] = (f16)v0[e]; hv[4 + e] = (f16)v1[e]; }
      *(f16x8*)&Bt[row][kc] = hv;
    }
    __syncthreads();
    #pragma unroll
    for (int ks = 0; ks < 2; ++ks) {
      f16x8 af[4], bf4[4];
      #pragma unroll
      for (int mi = 0; mi < 4; ++mi) af[mi]  = *(const f16x8*)&At[wr + mi * 16 + m16][ks * 32 + 8 * g];
      #pragma unroll
      for (int ni = 0; ni < 4; ++ni) bf4[ni] = *(const f16x8*)&Bt[wc + ni * 16 + m16][ks * 32 + 8 * g];
      #pragma unroll
      for (int mi = 0; mi < 4; ++mi)
        #pragma unroll
        for (int ni = 0; ni < 4; ++ni)
          acc[mi][ni] = MFMA16(af[mi], bf4[ni], acc[mi][ni]);
    }
  }
  #pragma unroll
  for (int mi = 0; mi < 4; ++mi)
    #pragma unroll
    for (int r = 0; r < 4; ++r) {
      int d = m0 + wr + mi * 16 + 4 * g + r;
      float bias = bm[d];
      #pragma unroll
      for (int ni = 0; ni < 4; ++ni) {
        int n = n0 + wc + ni * 16 + m16;
        hmT[(size_t)b * H_ * N_ + (size_t)d * N_ + n] = (f16)(acc[mi][ni][r] + bias);
      }
    }
}

// ---------------------------------------------------------------------------
// Flash attention + DTNN message, v4: BOTH K and V staged in LDS.
//   K from pre-swizzled Kimg (linear gld16);
//   V from linear hmT with the swizzle applied on the per-lane GLOBAL source
//   address (LDS dest stays linear, as global_load_lds requires).
// Single-buffered (75KB LDS -> 2 blocks/CU for TLP overlap of staging).
// ---------------------------------------------------------------------------
__global__ __launch_bounds__(256) void k_attn4(
    const f16* __restrict__ q, const float* __restrict__ mask,
    const f16* __restrict__ hmT, const f16* __restrict__ Kimg,
    f16* __restrict__ msg) {
  __shared__ __align__(16) f16 Kt[64 * 256];    // 32KB: K-tile, rows j (swizzled chunks)
  __shared__ __align__(16) f16 Vt[256 * 64];    // 32KB: V-tile, rows d (swizzled chunks)
  __shared__ __align__(16) f16 Plds[4][16][72];
  __shared__ float mask_lds[N_];
  const int tid = threadIdx.x, lane = tid & 63, wave = tid >> 6;
  const int g = lane >> 4, m16 = lane & 15;
  const int b = blockIdx.x, i0 = blockIdx.y * 64;

  mask_lds[tid]       = mask[b * N_ + tid];
  mask_lds[tid + 256] = mask[b * N_ + tid + 256];

  // Q fragments (fp16, rows i0 + wave*16 + m16)
  const f16* qp = q + (size_t)(b * N_ + i0 + wave * 16 + m16) * H_ + 8 * g;
  f16x8 qf[8];
  #pragma unroll
  for (int kb = 0; kb < 8; ++kb) qf[kb] = *(const f16x8*)(qp + kb * 32);

  f32x4 o[16] = {};
  float mrun[4], lrun[4];
  #pragma unroll
  for (int r = 0; r < 4; ++r) { mrun[r] = -3.0e38f; lrun[r] = 0.f; }

  const char* hvbs = (const char*)(hmT + (size_t)b * H_ * N_);
  const char* ksrc = (const char*)(Kimg + (size_t)b * N_ * H_);

  for (int jt = 0; jt < 8; ++jt) {
    const int j0 = jt * 64;
    // ---- stage K tile (64 j x 256 k): linear copy of pre-swizzled image
    {
      const char* s = ksrc + jt * 32768 + wave * 8192 + lane * 16;
      char* dst = (char*)Kt + wave * 8192;
      #pragma unroll
      for (int i = 0; i < 8; ++i) gld16(s + i * 1024, dst + i * 1024);
    }
    // ---- stage V tile (256 d x 64 j) from linear hmT, swizzle on source addr:
    // LDS row d slot s holds global chunk s^(d&7)  (chunk = 8 f16 = 16B).
    {
      int drow = wave * 64 + (lane >> 3);            // +8 per inst
      const char* s = hvbs + (size_t)drow * 1024 + jt * 128
                    + (((lane & 7) ^ ((lane >> 3) & 7)) << 4);
      char* dst = (char*)Vt + wave * 8192;
      #pragma unroll
      for (int i = 0; i < 8; ++i) gld16(s + (size_t)i * 8192, dst + i * 1024);
    }
    asm volatile("s_waitcnt vmcnt(0)" ::: "memory");
    __syncthreads();

    // ---- S = q·K^T: 16 rows x 64 cols per wave, XOR-deswizzled K reads
    f32x4 s[4] = {};
    __builtin_amdgcn_s_setprio(1);
    #pragma unroll
    for (int kb = 0; kb < 8; ++kb)
      #pragma unroll
      for (int cf = 0; cf < 4; ++cf) {
        const int jr = cf * 16 + m16;
        f16x8 kf = *(const f16x8*)&Kt[jr * 256 + (((kb * 4 + g) ^ (m16 & 7)) << 3)];
        s[cf] = MFMA16(qf[kb], kf, s[cf]);
      }
    __builtin_amdgcn_s_setprio(0);
    // ---- column mask
    #pragma unroll
    for (int cf = 0; cf < 4; ++cf) {
      float cm  = mask_lds[j0 + cf * 16 + m16];
      float add = NEGV * (1.f - cm);
      #pragma unroll
      for (int r = 0; r < 4; ++r) s[cf][r] += add;
    }
    // ---- online softmax (rows live in 16-lane groups)
    float p_[4][4];
    #pragma unroll
    for (int r = 0; r < 4; ++r) {
      float mx = fmaxf(fmaxf(s[0][r], s[1][r]), fmaxf(s[2][r], s[3][r]));
      #pragma unroll
      for (int off = 1; off < 16; off <<= 1) mx = fmaxf(mx, __shfl_xor(mx, off, 64));
      float mnew  = fmaxf(mrun[r], mx);
      float alpha = __expf(mrun[r] - mnew);
      float ps = 0.f;
      #pragma unroll
      for (int cf = 0; cf < 4; ++cf) {
        float pv = __expf(s[cf][r] - mnew);
        p_[cf][r] = pv; ps += pv;
      }
      #pragma unroll
      for (int off = 1; off < 16; off <<= 1) ps += __shfl_xor(ps, off, 64);
      lrun[r] = lrun[r] * alpha + ps;
      mrun[r] = mnew;
      #pragma unroll
      for (int c2 = 0; c2 < 16; ++c2) o[c2][r] *= alpha;
    }
    // ---- P -> LDS (C-layout) -> A-fragment layout (wave-local round trip)
    #pragma unroll
    for (int cf = 0; cf < 4; ++cf)
      #pragma unroll
      for (int r = 0; r < 4; ++r)
        Plds[wave][4 * g + r][cf * 16 + m16] = (f16)p_[cf][r];
    asm volatile("s_waitcnt lgkmcnt(0)" ::: "memory");
    __builtin_amdgcn_sched_barrier(0);
    f16x8 pa[2];
    #pragma unroll
    for (int ks = 0; ks < 2; ++ks) pa[ks] = *(const f16x8*)&Plds[wave][m16][ks * 32 + 8 * g];
    // ---- PV from LDS: o += P @ V-tile  (XOR-deswizzled V reads)
    __builtin_amdgcn_s_setprio(1);
    #pragma unroll
    for (int c2 = 0; c2 < 16; ++c2) {
      const int d = c2 * 16 + m16;
      f16x8 v0 = *(const f16x8*)&Vt[d * 64 + (((g)     ^ (m16 & 7)) << 3)];
      f16x8 v1 = *(const f16x8*)&Vt[d * 64 + (((4 + g) ^ (m16 & 7)) << 3)];
      o[c2] = MFMA16(pa[0], v0, o[c2]);
      o[c2] = MFMA16(pa[1], v1, o[c2]);
    }
    __builtin_amdgcn_s_setprio(0);
    __syncthreads();   // all reads of Kt/Vt done before next stage overwrites
  }

  // epilogue: msg = tanh(row_mask * O / l)
  #pragma unroll
  for (int r = 0; r < 4; ++r) {
    int irow = i0 + wave * 16 + 4 * g + r;
    float rm  = mask_lds[irow];
    float inv = rm / lrun[r];
    #pragma unroll
    for (int c2 = 0; c2 < 16; ++c2) {
      float val = tanhf(o[c2][r] * inv);
      msg[(size_t)(b * N_ + irow) * H_ + c2 * 16 + m16] = (f16)val;
    }
  }
}

// ---------------------------------------------------------------------------
// Gates: [z|r]_pre = [msg|h] @ WzrT^T + c_{z|r};  z = sigmoid, rh = sigmoid(r)*h
// Grid (512 m-tiles, 4 n-tiles).
// ---------------------------------------------------------------------------
__global__ __launch_bounds__(256) void k_gemm_zr(
    const f16* __restrict__ msg, const float* __restrict__ h,
    const f16* __restrict__ WzrT, const float* __restrict__ cz,
    const float* __restrict__ cr, f16* __restrict__ z, f16* __restrict__ rh) {
  __shared__ __align__(16) f16 At[128][72], Bt[128][72];
  const int tid = threadIdx.x, lane = tid & 63, wave = tid >> 6;
  const int g = lane >> 4, m16 = lane & 15;
  const int wr = (wave >> 1) * 64, wc = (wave & 1) * 64;
  const int m0 = blockIdx.x * 128, n0 = blockIdx.y * 128;
  f32x4 acc[4][4] = {};
  for (int k0 = 0; k0 < 512; k0 += 64) {
    __syncthreads();
    #pragma unroll
    for (int i = 0; i < 4; ++i) {
      int c = tid + i * 256;
      int row = c >> 3, kc = (c & 7) * 8;
      if (k0 < 256) {
        *(f16x8*)&At[row][kc] = *(const f16x8*)(msg + (size_t)(m0 + row) * 256 + k0 + kc);
      } else {
        const float* p = h + (size_t)(m0 + row) * 256 + (k0 - 256) + kc;
        f32x4 v0 = *(const f32x4*)p, v1 = *(const f32x4*)(p + 4);
        f16x8 hv;
        #pragma unroll
        for (int e = 0; e < 4; ++e) { hv[e] = (f16)v0[e]; hv[4 + e] = (f16)v1[e]; }
        *(f16x8*)&At[row][kc] = hv;
      }
      *(f16x8*)&Bt[row][kc] = *(const f16x8*)(WzrT + (size_t)(n0 + row) * 512 + k0 + kc);
    }
    __syncthreads();
    #pragma unroll
    for (int ks = 0; ks < 2; ++ks) {
      f16x8 af[4], bf4[4];
      #pragma unroll
      for (int mi = 0; mi < 4; ++mi) af[mi]  = *(const f16x8*)&At[wr + mi * 16 + m16][ks * 32 + 8 * g];
      #pragma unroll
      for (int ni = 0; ni < 4; ++ni) bf4[ni] = *(const f16x8*)&Bt[wc + ni * 16 + m16][ks * 32 + 8 * g];
      #pragma unroll
      for (int mi = 0; mi < 4; ++mi)
        #pragma unroll
        for (int ni = 0; ni < 4; ++ni)
          acc[mi][ni] = MFMA16(af[mi], bf4[ni], acc[mi][ni]);
    }
  }
  #pragma unroll
  for (int mi = 0; mi < 4; ++mi)
    #pragma unroll
    for (int ni = 0; ni < 4; ++ni) {
      int gcol = n0 + wc + ni * 16 + m16;
      #pragma unroll
      for (int r = 0; r < 4; ++r) {
        int grow = m0 + wr + mi * 16 + 4 * g + r;
        int bb = grow >> 9;
        float a = acc[mi][ni][r];
        if (gcol < 256) {
          float v = a + cz[bb * 256 + gcol];
          z[(size_t)grow * 256 + gcol] = (f16)(1.f / (1.f + __expf(-v)));
        } else {
          int c2 = gcol - 256;
          float v  = a + cr[bb * 256 + c2];
          float rr = 1.f / (1.f + __expf(-v));
          rh[(size_t)grow * 256 + c2] = (f16)(rr * h[(size_t)grow * 256 + c2]);
        }
      }
    }
}

// ---------------------------------------------------------------------------
// h_tilde = tanh([msg|r*h] @ WhcT^T + c_h);  out = (1-z)*h + z*h_tilde
// Grid (512 m-tiles, 2 n-tiles).
// ---------------------------------------------------------------------------
__global__ __launch_bounds__(256) void k_gemm_ht(
    const f16* __restrict__ msg, const f16* __restrict__ rh,
    const f16* __restrict__ WhcT, const float* __restrict__ ch,
    const f16* __restrict__ z, const float* __restrict__ h,
    float* __restrict__ out) {
  __shared__ __align__(16) f16 At[128][72], Bt[128][72];
  const int tid = threadIdx.x, lane = tid & 63, wave = tid >> 6;
  const int g = lane >> 4, m16 = lane & 15;
  const int wr = (wave >> 1) * 64, wc = (wave & 1) * 64;
  const int m0 = blockIdx.x * 128, n0 = blockIdx.y * 128;
  f32x4 acc[4][4] = {};
  for (int k0 = 0; k0 < 512; k0 += 64) {
    __syncthreads();
    const f16* asrc = (k0 < 256) ? msg : rh;
    int ak = k0 & 255;
    #pragma unroll
    for (int i = 0; i < 4; ++i) {
      int c = tid + i * 256;
      int row = c >> 3, kc = (c & 7) * 8;
      *(f16x8*)&At[row][kc] = *(const f16x8*)(asrc + (size_t)(m0 + row) * 256 + ak + kc);
      *(f16x8*)&Bt[row][kc] = *(const f16x8*)(WhcT + (size_t)(n0 + row) * 512 + k0 + kc);
    }
    __syncthreads();
    #pragma unroll
    for (int ks = 0; ks < 2; ++ks) {
      f16x8 af[4], bf4[4];
      #pragma unroll
      for (int mi = 0; mi < 4; ++mi) af[mi]  = *(const f16x8*)&At[wr + mi * 16 + m16][ks * 32 + 8 * g];
      #pragma unroll
      for (int ni = 0; ni < 4; ++ni) bf4[ni] = *(const f16x8*)&Bt[wc + ni * 16 + m16][ks * 32 + 8 * g];
      #pragma unroll
      for (int mi = 0; mi < 4; ++mi)
        #pragma unroll
        for (int ni = 0; ni < 4; ++ni)
          acc[mi][ni] = MFMA16(af[mi], bf4[ni], acc[mi][ni]);
    }
  }
  #pragma unroll
  for (int mi = 0; mi < 4; ++mi)
    #pragma unroll
    for (int ni = 0; ni < 4; ++ni) {
      int gcol = n0 + wc + ni * 16 + m16;
      #pragma unroll
      for (int r = 0; r < 4; ++r) {
        int grow = m0 + wr + mi * 16 + 4 * g + r;
        int bb = grow >> 9;
        size_t oidx = (size_t)grow * 256 + gcol;
        float pre = acc[mi][ni][r] + ch[bb * 256 + gcol];
        float htl = tanhf(pre);
        float zv  = (float)z[oidx];
        float hv  = h[oidx];
        out[oidx] = (1.f - zv) * hv + zv * htl;
      }
    }
}

// ---------------------------------------------------------------------------
extern "C" void kernel_launch(void* const* d_in, const int* in_sizes, int n_in,
                              void* d_out, int out_size, void* d_ws, size_t ws_size,
                              hipStream_t stream) {
  const float* h    = (const float*)d_in[0];
  const float* jets = (const float*)d_in[1];
  const float* mask = (const float*)d_in[2];
  const float* Wa   = (const float*)d_in[3];
  const float* ba   = (const float*)d_in[4];
  const float* Wm   = (const float*)d_in[5];
  const float* bm   = (const float*)d_in[6];
  const float* Wz   = (const float*)d_in[7];
  const float* bz   = (const float*)d_in[8];
  const float* Wr   = (const float*)d_in[9];
  const float* br   = (const float*)d_in[10];
  const float* Wh   = (const float*)d_in[11];
  const float* bh   = (const float*)d_in[12];
  float* out = (float*)d_out;

  char* ws = (char*)d_ws;
  size_t off = 0;
  auto alloc = [&](size_t bytes) -> void* {
    void* p = ws + off;
    off += (bytes + 255) & ~(size_t)255;
    return p;
  };
  // big: q (f16, 32MB) during attention; z (f16) + rh (f16) afterwards.
  char*   big   = (char*) alloc((size_t)ROWS * H_ * 4);
  f16*    hmT   = (f16*)  alloc((size_t)B_ * H_ * N_ * 2);
  f16*    msg   = (f16*)  alloc((size_t)ROWS * H_ * 2);
  f16*    Kimg  = (f16*)  alloc((size_t)ROWS * H_ * 2);
  float*  hmean4= (float*)alloc((size_t)B_ * 4 * H_ * 4);
  float*  cz    = (float*)alloc((size_t)B_ * H_ * 4);
  float*  cr    = (float*)alloc((size_t)B_ * H_ * 4);
  float*  chv   = (float*)alloc((size_t)B_ * H_ * 4);
  f16*    WaT   = (f16*)  alloc(65536 * 2);
  f16*    WmT   = (f16*)  alloc(65536 * 2);
  f16*    WzrT  = (f16*)  alloc(262144 * 2);
  f16*    WhcT  = (f16*)  alloc(131072 * 2);
  f16* q  = (f16*)big;
  f16* z  = (f16*)big;                                     // q dead after attn
  f16* rh = (f16*)(big + (size_t)ROWS * H_ * 2);
  if (off > ws_size) return;  // workspace insufficient

  k_prep    <<<2048, 256, 0, stream>>>(Wa, Wm, Wz, Wr, Wh, WaT, WmT, WzrT, WhcT);
  k_hmean   <<<dim3(B_, 4), H_, 0, stream>>>(h, hmean4);
  k_cvec    <<<B_, H_, 0, stream>>>(hmean4, jets, Wz, Wr, Wh, bz, br, bh, cz, cr, chv);
  k_kimg    <<<8192, 256, 0, stream>>>(h, Kimg);
  k_gemm_q  <<<dim3(512, 2), 256, 0, stream>>>(h, WaT, ba, q);
  k_gemm_hmT<<<dim3(128, 8), 256, 0, stream>>>(h, WmT, bm, hmT);
  k_attn4   <<<dim3(128, 8), 256, 0, stream>>>(q, mask, hmT, Kimg, msg);
  k_gemm_zr <<<dim3(512, 4), 256, 0, stream>>>(msg, h, WzrT, cz, cr, z, rh);
  k_gemm_ht <<<dim3(512, 2), 256, 0, stream>>>(msg, rh, WhcT, chv, z, h, out);
}